// Round 8
// baseline (597.803 us; speedup 1.0000x reference)
//
#include <hip/hip_runtime.h>
#include <hip/hip_fp16.h>
#include <math.h>

static constexpr int ST   = 32;   // halfs per g-row  (64 B rows)
static constexpr int HFST = 16;   // halfs per hf-row (32 B rows)

// Bucketing: bucket = dst >> BSHIFT (128 nodes per bucket).
static constexpr int BSHIFT = 7;
static constexpr int BSZ    = 1 << BSHIFT;
static constexpr int NB     = 1024;         // covers n < 131072
static constexpr int NBLK   = 512;          // blocks for hist/partition passes

// ---- pass 1: per-block LDS histogram of dst buckets ------------------------
__global__ __launch_bounds__(1024) void k_p1_hist(const int* __restrict__ dst, int ne,
                                                  int* __restrict__ bc) {
    __shared__ int hist[NB];
    int blk = blockIdx.x, tid = threadIdx.x;
    for (int i = tid; i < NB; i += blockDim.x) hist[i] = 0;
    __syncthreads();
    int chunk = (((ne + NBLK - 1) / NBLK) + 3) & ~3;
    int beg = blk * chunk, end = min(beg + chunk, ne);
    for (int i = beg + tid * 4; i < end; i += blockDim.x * 4) {
        if (i + 3 < end) {
            int4 d = *reinterpret_cast<const int4*>(dst + i);
            atomicAdd(&hist[d.x >> BSHIFT], 1);
            atomicAdd(&hist[d.y >> BSHIFT], 1);
            atomicAdd(&hist[d.z >> BSHIFT], 1);
            atomicAdd(&hist[d.w >> BSHIFT], 1);
        } else {
            for (int k = i; k < end; ++k) atomicAdd(&hist[dst[k] >> BSHIFT], 1);
        }
    }
    __syncthreads();
    for (int b = tid; b < NB; b += blockDim.x)
        bc[b * NBLK + blk] = hist[b];
}

// ---- pass 2: single-block exclusive scan of bc[NB*NBLK] --------------------
__global__ __launch_bounds__(1024) void k_p2_scan(int* __restrict__ bc,
                                                  int* __restrict__ bucket_base,
                                                  int* __restrict__ row_start,
                                                  int n, int ne) {
    __shared__ int partial[1024];
    const int M = NB * NBLK;
    int tid = threadIdx.x;
    int seg = M / 1024;
    int beg = tid * seg, end = beg + seg;
    int s = 0;
    for (int i = beg; i < end; ++i) s += bc[i];
    partial[tid] = s;
    __syncthreads();
    for (int off = 1; off < 1024; off <<= 1) {
        int val = (tid >= off) ? partial[tid - off] : 0;
        __syncthreads();
        partial[tid] += val;
        __syncthreads();
    }
    int run = (tid == 0) ? 0 : partial[tid - 1];
    for (int i = beg; i < end; ++i) {
        int t = bc[i];
        bc[i] = run;
        run += t;
    }
    __syncthreads();
    for (int b = tid; b < NB; b += 1024) bucket_base[b] = bc[b * NBLK];
    if (tid == 0) { bucket_base[NB] = ne; row_start[n] = ne; }
}

// ---- pass 3: partition packed (dlocal<<20 | src) by bucket -----------------
__global__ __launch_bounds__(1024) void k_p3_partition(const int* __restrict__ src,
                                                       const int* __restrict__ dst,
                                                       int ne, const int* __restrict__ bc,
                                                       int* __restrict__ ep) {
    __shared__ int cur[NB];
    int blk = blockIdx.x, tid = threadIdx.x;
    for (int b = tid; b < NB; b += blockDim.x) cur[b] = bc[b * NBLK + blk];
    __syncthreads();
    int chunk = (((ne + NBLK - 1) / NBLK) + 3) & ~3;
    int beg = blk * chunk, end = min(beg + chunk, ne);
    for (int i = beg + tid * 4; i < end; i += blockDim.x * 4) {
        if (i + 3 < end) {
            int4 d = *reinterpret_cast<const int4*>(dst + i);
            int4 sv = *reinterpret_cast<const int4*>(src + i);
            int p0 = atomicAdd(&cur[d.x >> BSHIFT], 1);
            ep[p0] = sv.x | ((d.x & (BSZ - 1)) << 20);
            int p1 = atomicAdd(&cur[d.y >> BSHIFT], 1);
            ep[p1] = sv.y | ((d.y & (BSZ - 1)) << 20);
            int p2 = atomicAdd(&cur[d.z >> BSHIFT], 1);
            ep[p2] = sv.z | ((d.z & (BSZ - 1)) << 20);
            int p3 = atomicAdd(&cur[d.w >> BSHIFT], 1);
            ep[p3] = sv.w | ((d.w & (BSZ - 1)) << 20);
        } else {
            for (int k = i; k < end; ++k) {
                int d = dst[k];
                int pos = atomicAdd(&cur[d >> BSHIFT], 1);
                ep[pos] = src[k] | ((d & (BSZ - 1)) << 20);
            }
        }
    }
}

// ---- pass 4: one block per bucket -> csr, row_start, dinv ------------------
__global__ void k_p4_build(const int* __restrict__ ep,
                           const int* __restrict__ bucket_base,
                           int* __restrict__ csr, int* __restrict__ row_start,
                           float* __restrict__ dinv, int n) {
    __shared__ int cnt[BSZ];
    __shared__ int off[BSZ];
    int b = blockIdx.x, tid = threadIdx.x;
    int node_base = b << BSHIFT;
    if (node_base >= n) return;
    int ebeg = bucket_base[b], eend = bucket_base[b + 1];
    for (int i = tid; i < BSZ; i += blockDim.x) cnt[i] = 0;
    __syncthreads();
    for (int e = ebeg + tid; e < eend; e += blockDim.x)
        atomicAdd(&cnt[(ep[e] >> 20) & (BSZ - 1)], 1);
    __syncthreads();
    // parallel inclusive scan (Hillis-Steele) over BSZ counters
    if (tid < BSZ) off[tid] = cnt[tid];
    __syncthreads();
    for (int d = 1; d < BSZ; d <<= 1) {
        int v = (tid < BSZ && tid >= d) ? off[tid - d] : 0;
        __syncthreads();
        if (tid < BSZ) off[tid] += v;
        __syncthreads();
    }
    int nb = min(BSZ, n - node_base);
    if (tid < nb) {
        int c = cnt[tid];
        row_start[node_base + tid] = ebeg + off[tid] - c;   // exclusive
        dinv[node_base + tid] = rsqrtf((float)(c + 1));
    }
    __syncthreads();
    if (tid < BSZ) cnt[tid] = off[tid] - cnt[tid];          // cursors = exclusive
    __syncthreads();
    for (int e = ebeg + tid; e < eend; e += blockDim.x) {
        int p = ep[e];
        int loc = atomicAdd(&cnt[(p >> 20) & (BSZ - 1)], 1);
        csr[ebeg + loc] = p & 0xFFFFF;
    }
}

// ---- conv1 node-linear: g1 = fp16( dinv[v] * (x @ W1) ) --------------------
__global__ void k_nl1(const float* __restrict__ x, int xs,
                      const float* __restrict__ W, const float* __restrict__ dinv,
                      __half* __restrict__ g, int n) {
    int t = blockIdx.x * blockDim.x + threadIdx.x;
    int v = t >> 5, j = t & 31;
    if (v >= n) return;
    float a = 0.0f;
    if (j < 18) {
        const float* xr = x + (size_t)v * xs;
        #pragma unroll
        for (int i = 0; i < 10; ++i) a += xr[i] * W[i * 18 + j];
        a *= dinv[v];
    }
    g[(size_t)v * ST + j] = __float2half(a);
}

// Unroll-8 pipelined neighbor gather: 8 independent row loads in flight.
__device__ __forceinline__ float gather_row(const int* __restrict__ csr,
                                            int beg, int end,
                                            const __half* __restrict__ gf) {
    float a = 0.0f, a0 = 0.0f, a1 = 0.0f, a2 = 0.0f, a3 = 0.0f;
    int e = beg;
    for (; e + 8 <= end; e += 8) {
        int s0 = csr[e],     s1 = csr[e + 1], s2 = csr[e + 2], s3 = csr[e + 3];
        int s4 = csr[e + 4], s5 = csr[e + 5], s6 = csr[e + 6], s7 = csr[e + 7];
        float v0 = __half2float(gf[(size_t)s0 * ST]);
        float v1 = __half2float(gf[(size_t)s1 * ST]);
        float v2 = __half2float(gf[(size_t)s2 * ST]);
        float v3 = __half2float(gf[(size_t)s3 * ST]);
        float v4 = __half2float(gf[(size_t)s4 * ST]);
        float v5 = __half2float(gf[(size_t)s5 * ST]);
        float v6 = __half2float(gf[(size_t)s6 * ST]);
        float v7 = __half2float(gf[(size_t)s7 * ST]);
        a0 += v0 + v4; a1 += v1 + v5; a2 += v2 + v6; a3 += v3 + v7;
    }
    for (; e < end; ++e) a += __half2float(gf[(size_t)csr[e] * ST]);
    return a + (a0 + a1) + (a2 + a3);
}

// ---- fused: gather-finish(conv DP) + node-linear(DP->DN) -------------------
template<int DP, int DN>
__global__ void k_gfnl(const int* __restrict__ row, const int* __restrict__ csr,
                       const __half* __restrict__ gin, const float* __restrict__ dinv,
                       const float* __restrict__ bias, const float* __restrict__ W,
                       __half* __restrict__ gout, int n) {
    __shared__ float h_lds[8][ST];
    int t = blockIdx.x * 256 + threadIdx.x;
    int v = t >> 5, f = t & 31, ln = threadIdx.x >> 5;
    float dv = 0.0f, r = 0.0f;
    if (v < n) {
        dv = dinv[v];
        if (f < DP) {
            float a = __half2float(gin[(size_t)v * ST + f]);
            a += gather_row(csr, row[v], row[v + 1], gin + f);
            r = tanhf(dv * a + bias[f]);
        }
    }
    h_lds[ln][f] = r;
    __syncthreads();
    if (v < n) {
        float a = 0.0f;
        if (f < DN) {
            #pragma unroll
            for (int i = 0; i < DP; ++i) a += h_lds[ln][i] * W[i * DN + f];
            a *= dv;
        }
        gout[(size_t)v * ST + f] = __float2half(a);
    }
}

// ---- fused: gather-finish(conv3, DP=20) + MLP 20->24->18->12 -> hf fp16 ----
__global__ void k_gfmlp(const int* __restrict__ row, const int* __restrict__ csr,
                        const __half* __restrict__ gin, const float* __restrict__ dinv,
                        const float* __restrict__ b3,
                        const float* __restrict__ L1w, const float* __restrict__ L1b,
                        const float* __restrict__ L2w, const float* __restrict__ L2b,
                        const float* __restrict__ L3w, const float* __restrict__ L3b,
                        __half* __restrict__ hf, int n) {
    __shared__ float A[8][ST];
    __shared__ float Bx[8][ST];
    int t = blockIdx.x * 256 + threadIdx.x;
    int v = t >> 5, f = t & 31, ln = threadIdx.x >> 5;
    float r = 0.0f;
    if (v < n && f < 20) {
        float a = __half2float(gin[(size_t)v * ST + f]);
        a += gather_row(csr, row[v], row[v + 1], gin + f);
        r = tanhf(dinv[v] * a + b3[f]);
    }
    A[ln][f] = r;
    __syncthreads();
    float s1 = 0.0f;
    if (v < n && f < 24) {
        float s = L1b[f];
        #pragma unroll
        for (int i = 0; i < 20; ++i) s += A[ln][i] * L1w[i * 24 + f];
        s1 = tanhf(s);
    }
    Bx[ln][f] = s1;
    __syncthreads();
    float s2 = 0.0f;
    if (v < n && f < 18) {
        float s = L2b[f];
        #pragma unroll
        for (int i = 0; i < 24; ++i) s += Bx[ln][i] * L2w[i * 18 + f];
        s2 = tanhf(s);
    }
    A[ln][f] = s2;
    __syncthreads();
    if (v < n && f < HFST) {
        float o = 0.0f;
        if (f < 12) {
            float s = L3b[f];
            #pragma unroll
            for (int i = 0; i < 18; ++i) s += A[ln][i] * L3w[i * 12 + f];
            o = tanhf(s);
        }
        hf[(size_t)v * HFST + f] = __float2half(o);
    }
}

// ---- Edge head: e_row = [hf[src], hf[dst]]; out = e_row @ Cw + Cb ----------
__global__ void k_edge(const int* __restrict__ src, const int* __restrict__ dst,
                       const __half* __restrict__ hf,
                       const float* __restrict__ Cw, const float* __restrict__ Cb,
                       float* __restrict__ out, float* __restrict__ eout, int ne) {
    int e = blockIdx.x * blockDim.x + threadIdx.x;
    if (e >= ne) return;
    int s = src[e], d = dst[e];
    float v[24];
    const __half2* hs = reinterpret_cast<const __half2*>(hf + (size_t)s * HFST);
    const __half2* hd = reinterpret_cast<const __half2*>(hf + (size_t)d * HFST);
    #pragma unroll
    for (int k = 0; k < 6; ++k) {
        float2 t = __half22float2(hs[k]);
        v[2 * k] = t.x; v[2 * k + 1] = t.y;
    }
    #pragma unroll
    for (int k = 0; k < 6; ++k) {
        float2 t = __half22float2(hd[k]);
        v[12 + 2 * k] = t.x; v[12 + 2 * k + 1] = t.y;
    }
    float o0 = Cb[0], o1 = Cb[1], o2 = Cb[2];
    #pragma unroll
    for (int k = 0; k < 24; ++k) {
        o0 += v[k] * Cw[k * 3 + 0];
        o1 += v[k] * Cw[k * 3 + 1];
        o2 += v[k] * Cw[k * 3 + 2];
    }
    float* op = out + (size_t)e * 3;
    op[0] = o0; op[1] = o1; op[2] = o2;
    float4* epv = reinterpret_cast<float4*>(eout + (size_t)e * 24);
    #pragma unroll
    for (int k = 0; k < 6; ++k) epv[k] = reinterpret_cast<const float4*>(v)[k];
}

static inline char* align64(char* p) {
    return (char*)(((uintptr_t)p + 63) & ~(uintptr_t)63);
}

extern "C" void kernel_launch(void* const* d_in, const int* in_sizes, int n_in,
                              void* d_out, int out_size, void* d_ws, size_t ws_size,
                              hipStream_t stream) {
    const float* x  = (const float*)d_in[0];
    const int*   ei = (const int*)d_in[1];
    const int n  = in_sizes[2];
    const int ne = in_sizes[1] / 2;
    const int F  = in_sizes[0] / n;    // 10
    const int* src  = ei;
    const int* dstp = ei + ne;

    const float *W1 = (const float*)d_in[3],  *b1 = (const float*)d_in[4];
    const float *W2 = (const float*)d_in[5],  *b2 = (const float*)d_in[6];
    const float *W3 = (const float*)d_in[7],  *b3 = (const float*)d_in[8];
    const float *L1w = (const float*)d_in[9],  *L1b = (const float*)d_in[10];
    const float *L2w = (const float*)d_in[11], *L2b = (const float*)d_in[12];
    const float *L3w = (const float*)d_in[13], *L3b = (const float*)d_in[14];
    const float *Cw  = (const float*)d_in[15], *Cb  = (const float*)d_in[16];

    // Workspace layout
    char* p = (char*)d_ws;
    int* csr = (int*)p;                    p += (size_t)ne * 4;
    int* epk = (int*)p;                    p += (size_t)ne * 4;
    int* bc  = (int*)p;                    p += (size_t)NB * NBLK * 4;
    int* row = (int*)p;                    p += ((size_t)n + 4) * 4;
    int* bucket_base = (int*)p;            p += ((size_t)NB + 4) * 4;
    float* dinv = (float*)p;               p += (size_t)n * 4;
    p = align64(p);
    __half* g1 = (__half*)p;               p += (size_t)n * ST * 2;
    p = align64(p);
    __half* g2 = (__half*)p;               p += (size_t)n * ST * 2;
    p = align64(p);
    __half* hf = (__half*)p;               p += (size_t)n * HFST * 2;

    const int B = 256;
    const int gb_n32 = (n * 32 + B - 1) / B;
    const int gb_e   = (ne + B - 1) / B;

    // CSR build: LDS counting sort, no global atomics
    k_p1_hist<<<NBLK, 1024, 0, stream>>>(dstp, ne, bc);
    k_p2_scan<<<1, 1024, 0, stream>>>(bc, bucket_base, row, n, ne);
    k_p3_partition<<<NBLK, 1024, 0, stream>>>(src, dstp, ne, bc, epk);
    k_p4_build<<<NB, B, 0, stream>>>(epk, bucket_base, csr, row, dinv, n);

    // conv1 linear
    k_nl1<<<gb_n32, B, 0, stream>>>(x, F, W1, dinv, g1, n);
    // conv1 gather+finish fused with conv2 linear -> g2
    k_gfnl<18, 24><<<gb_n32, B, 0, stream>>>(row, csr, g1, dinv, b1, W2, g2, n);
    // conv2 gather+finish fused with conv3 linear -> g1
    k_gfnl<24, 20><<<gb_n32, B, 0, stream>>>(row, csr, g2, dinv, b2, W3, g1, n);
    // conv3 gather+finish fused with MLP -> hf (fp16)
    k_gfmlp<<<gb_n32, B, 0, stream>>>(row, csr, g1, dinv, b3,
                                      L1w, L1b, L2w, L2b, L3w, L3b, hf, n);

    // edge head
    float* out_p = (float*)d_out;
    float* e_p   = out_p + (size_t)ne * 3;
    k_edge<<<gb_e, B, 0, stream>>>(src, dstp, hf, Cw, Cb, out_p, e_p, ne);
}

// Round 9
// 411.468 us; speedup vs baseline: 1.4529x; 1.4529x over previous
//
#include <hip/hip_runtime.h>
#include <hip/hip_fp16.h>
#include <math.h>

static constexpr int ST   = 32;   // halfs per g-row  (64 B rows)
static constexpr int HFST = 16;   // halfs per hf-row (32 B rows)

// Bucketing: bucket = dst >> BSHIFT (128 nodes per bucket).
static constexpr int BSHIFT = 7;
static constexpr int BSZ    = 1 << BSHIFT;
static constexpr int NB     = 1024;         // covers n < 131072
static constexpr int NBLK   = 512;          // blocks for hist/partition passes

// ---- pass 1: per-block LDS histogram of dst buckets ------------------------
__global__ __launch_bounds__(1024) void k_p1_hist(const int* __restrict__ dst, int ne,
                                                  int* __restrict__ bc) {
    __shared__ int hist[NB];
    int blk = blockIdx.x, tid = threadIdx.x;
    for (int i = tid; i < NB; i += blockDim.x) hist[i] = 0;
    __syncthreads();
    int chunk = (((ne + NBLK - 1) / NBLK) + 3) & ~3;
    int beg = blk * chunk, end = min(beg + chunk, ne);
    for (int i = beg + tid * 4; i < end; i += blockDim.x * 4) {
        if (i + 3 < end) {
            int4 d = *reinterpret_cast<const int4*>(dst + i);
            atomicAdd(&hist[d.x >> BSHIFT], 1);
            atomicAdd(&hist[d.y >> BSHIFT], 1);
            atomicAdd(&hist[d.z >> BSHIFT], 1);
            atomicAdd(&hist[d.w >> BSHIFT], 1);
        } else {
            for (int k = i; k < end; ++k) atomicAdd(&hist[dst[k] >> BSHIFT], 1);
        }
    }
    __syncthreads();
    for (int b = tid; b < NB; b += blockDim.x)
        bc[b * NBLK + blk] = hist[b];
}

// ---- pass 2a: per-bucket totals S[b] = sum_blk bc[b][blk] ------------------
__global__ __launch_bounds__(256) void k_p2a_sum(const int* __restrict__ bc,
                                                 int* __restrict__ S) {
    __shared__ int red[256];
    int b = blockIdx.x, tid = threadIdx.x;
    const int* r = bc + (size_t)b * NBLK;
    int s = 0;
    for (int i = tid; i < NBLK; i += 256) s += r[i];
    red[tid] = s;
    __syncthreads();
    for (int off = 128; off > 0; off >>= 1) {
        if (tid < off) red[tid] += red[tid + off];
        __syncthreads();
    }
    if (tid == 0) S[b] = red[0];
}

// ---- pass 2b: single-block scan of S[NB] -> bucket_base --------------------
__global__ __launch_bounds__(1024) void k_p2b_scan(const int* __restrict__ S,
                                                   int* __restrict__ bucket_base,
                                                   int* __restrict__ row_start,
                                                   int n, int ne) {
    __shared__ int part[1024];
    int tid = threadIdx.x;
    int v = (tid < NB) ? S[tid] : 0;
    part[tid] = v;
    __syncthreads();
    for (int off = 1; off < 1024; off <<= 1) {
        int t = (tid >= off) ? part[tid - off] : 0;
        __syncthreads();
        part[tid] += t;
        __syncthreads();
    }
    if (tid < NB) bucket_base[tid] = part[tid] - v;   // exclusive
    if (tid == 0) { bucket_base[NB] = ne; row_start[n] = ne; }
}

// ---- pass 2c: per-bucket exclusive scan of bc[b][*] + bucket_base[b] -------
__global__ __launch_bounds__(NBLK) void k_p2c_scan(int* __restrict__ bc,
                                                   const int* __restrict__ bucket_base) {
    __shared__ int part[NBLK];
    int b = blockIdx.x, tid = threadIdx.x;
    int* r = bc + (size_t)b * NBLK;
    int v = r[tid];
    part[tid] = v;
    __syncthreads();
    for (int off = 1; off < NBLK; off <<= 1) {
        int t = (tid >= off) ? part[tid - off] : 0;
        __syncthreads();
        part[tid] += t;
        __syncthreads();
    }
    r[tid] = bucket_base[b] + part[tid] - v;          // exclusive
}

// ---- pass 3: partition packed (dlocal<<20 | src) by bucket -----------------
__global__ __launch_bounds__(1024) void k_p3_partition(const int* __restrict__ src,
                                                       const int* __restrict__ dst,
                                                       int ne, const int* __restrict__ bc,
                                                       int* __restrict__ ep) {
    __shared__ int cur[NB];
    int blk = blockIdx.x, tid = threadIdx.x;
    for (int b = tid; b < NB; b += blockDim.x) cur[b] = bc[b * NBLK + blk];
    __syncthreads();
    int chunk = (((ne + NBLK - 1) / NBLK) + 3) & ~3;
    int beg = blk * chunk, end = min(beg + chunk, ne);
    for (int i = beg + tid * 4; i < end; i += blockDim.x * 4) {
        if (i + 3 < end) {
            int4 d = *reinterpret_cast<const int4*>(dst + i);
            int4 sv = *reinterpret_cast<const int4*>(src + i);
            int p0 = atomicAdd(&cur[d.x >> BSHIFT], 1);
            ep[p0] = sv.x | ((d.x & (BSZ - 1)) << 20);
            int p1 = atomicAdd(&cur[d.y >> BSHIFT], 1);
            ep[p1] = sv.y | ((d.y & (BSZ - 1)) << 20);
            int p2 = atomicAdd(&cur[d.z >> BSHIFT], 1);
            ep[p2] = sv.z | ((d.z & (BSZ - 1)) << 20);
            int p3 = atomicAdd(&cur[d.w >> BSHIFT], 1);
            ep[p3] = sv.w | ((d.w & (BSZ - 1)) << 20);
        } else {
            for (int k = i; k < end; ++k) {
                int d = dst[k];
                int pos = atomicAdd(&cur[d >> BSHIFT], 1);
                ep[pos] = src[k] | ((d & (BSZ - 1)) << 20);
            }
        }
    }
}

// ---- pass 4: one block per bucket -> csr, row_start, dinv ------------------
__global__ void k_p4_build(const int* __restrict__ ep,
                           const int* __restrict__ bucket_base,
                           int* __restrict__ csr, int* __restrict__ row_start,
                           float* __restrict__ dinv, int n) {
    __shared__ int cnt[BSZ];
    __shared__ int off[BSZ];
    int b = blockIdx.x, tid = threadIdx.x;
    int node_base = b << BSHIFT;
    if (node_base >= n) return;
    int ebeg = bucket_base[b], eend = bucket_base[b + 1];
    for (int i = tid; i < BSZ; i += blockDim.x) cnt[i] = 0;
    __syncthreads();
    for (int e = ebeg + tid; e < eend; e += blockDim.x)
        atomicAdd(&cnt[(ep[e] >> 20) & (BSZ - 1)], 1);
    __syncthreads();
    if (tid < BSZ) off[tid] = cnt[tid];
    __syncthreads();
    for (int d = 1; d < BSZ; d <<= 1) {
        int v = (tid < BSZ && tid >= d) ? off[tid - d] : 0;
        __syncthreads();
        if (tid < BSZ) off[tid] += v;
        __syncthreads();
    }
    int nb = min(BSZ, n - node_base);
    if (tid < nb) {
        int c = cnt[tid];
        row_start[node_base + tid] = ebeg + off[tid] - c;   // exclusive
        dinv[node_base + tid] = rsqrtf((float)(c + 1));
    }
    __syncthreads();
    if (tid < BSZ) cnt[tid] = off[tid] - cnt[tid];          // cursors = exclusive
    __syncthreads();
    for (int e = ebeg + tid; e < eend; e += blockDim.x) {
        int p = ep[e];
        int loc = atomicAdd(&cnt[(p >> 20) & (BSZ - 1)], 1);
        csr[ebeg + loc] = p & 0xFFFFF;
    }
}

// ---- conv1 node-linear: g1 = fp16( dinv[v] * (x @ W1) ) --------------------
__global__ void k_nl1(const float* __restrict__ x, int xs,
                      const float* __restrict__ W, const float* __restrict__ dinv,
                      __half* __restrict__ g, int n) {
    int t = blockIdx.x * blockDim.x + threadIdx.x;
    int v = t >> 5, j = t & 31;
    if (v >= n) return;
    float a = 0.0f;
    if (j < 18) {
        const float* xr = x + (size_t)v * xs;
        #pragma unroll
        for (int i = 0; i < 10; ++i) a += xr[i] * W[i * 18 + j];
        a *= dinv[v];
    }
    g[(size_t)v * ST + j] = __float2half(a);
}

// Unroll-8 pipelined neighbor gather: 8 independent row loads in flight.
__device__ __forceinline__ float gather_row(const int* __restrict__ csr,
                                            int beg, int end,
                                            const __half* __restrict__ gf) {
    float a = 0.0f, a0 = 0.0f, a1 = 0.0f, a2 = 0.0f, a3 = 0.0f;
    int e = beg;
    for (; e + 8 <= end; e += 8) {
        int s0 = csr[e],     s1 = csr[e + 1], s2 = csr[e + 2], s3 = csr[e + 3];
        int s4 = csr[e + 4], s5 = csr[e + 5], s6 = csr[e + 6], s7 = csr[e + 7];
        float v0 = __half2float(gf[(size_t)s0 * ST]);
        float v1 = __half2float(gf[(size_t)s1 * ST]);
        float v2 = __half2float(gf[(size_t)s2 * ST]);
        float v3 = __half2float(gf[(size_t)s3 * ST]);
        float v4 = __half2float(gf[(size_t)s4 * ST]);
        float v5 = __half2float(gf[(size_t)s5 * ST]);
        float v6 = __half2float(gf[(size_t)s6 * ST]);
        float v7 = __half2float(gf[(size_t)s7 * ST]);
        a0 += v0 + v4; a1 += v1 + v5; a2 += v2 + v6; a3 += v3 + v7;
    }
    for (; e < end; ++e) a += __half2float(gf[(size_t)csr[e] * ST]);
    return a + (a0 + a1) + (a2 + a3);
}

// ---- fused: gather-finish(conv DP) + node-linear(DP->DN) -------------------
template<int DP, int DN>
__global__ void k_gfnl(const int* __restrict__ row, const int* __restrict__ csr,
                       const __half* __restrict__ gin, const float* __restrict__ dinv,
                       const float* __restrict__ bias, const float* __restrict__ W,
                       __half* __restrict__ gout, int n) {
    __shared__ float h_lds[8][ST];
    int t = blockIdx.x * 256 + threadIdx.x;
    int v = t >> 5, f = t & 31, ln = threadIdx.x >> 5;
    float dv = 0.0f, r = 0.0f;
    if (v < n) {
        dv = dinv[v];
        if (f < DP) {
            float a = __half2float(gin[(size_t)v * ST + f]);
            a += gather_row(csr, row[v], row[v + 1], gin + f);
            r = tanhf(dv * a + bias[f]);
        }
    }
    h_lds[ln][f] = r;
    __syncthreads();
    if (v < n) {
        float a = 0.0f;
        if (f < DN) {
            #pragma unroll
            for (int i = 0; i < DP; ++i) a += h_lds[ln][i] * W[i * DN + f];
            a *= dv;
        }
        gout[(size_t)v * ST + f] = __float2half(a);
    }
}

// ---- fused: gather-finish(conv3, DP=20) + MLP 20->24->18->12 -> hf fp16 ----
__global__ void k_gfmlp(const int* __restrict__ row, const int* __restrict__ csr,
                        const __half* __restrict__ gin, const float* __restrict__ dinv,
                        const float* __restrict__ b3,
                        const float* __restrict__ L1w, const float* __restrict__ L1b,
                        const float* __restrict__ L2w, const float* __restrict__ L2b,
                        const float* __restrict__ L3w, const float* __restrict__ L3b,
                        __half* __restrict__ hf, int n) {
    __shared__ float A[8][ST];
    __shared__ float Bx[8][ST];
    int t = blockIdx.x * 256 + threadIdx.x;
    int v = t >> 5, f = t & 31, ln = threadIdx.x >> 5;
    float r = 0.0f;
    if (v < n && f < 20) {
        float a = __half2float(gin[(size_t)v * ST + f]);
        a += gather_row(csr, row[v], row[v + 1], gin + f);
        r = tanhf(dinv[v] * a + b3[f]);
    }
    A[ln][f] = r;
    __syncthreads();
    float s1 = 0.0f;
    if (v < n && f < 24) {
        float s = L1b[f];
        #pragma unroll
        for (int i = 0; i < 20; ++i) s += A[ln][i] * L1w[i * 24 + f];
        s1 = tanhf(s);
    }
    Bx[ln][f] = s1;
    __syncthreads();
    float s2 = 0.0f;
    if (v < n && f < 18) {
        float s = L2b[f];
        #pragma unroll
        for (int i = 0; i < 24; ++i) s += Bx[ln][i] * L2w[i * 18 + f];
        s2 = tanhf(s);
    }
    A[ln][f] = s2;
    __syncthreads();
    if (v < n && f < HFST) {
        float o = 0.0f;
        if (f < 12) {
            float s = L3b[f];
            #pragma unroll
            for (int i = 0; i < 18; ++i) s += A[ln][i] * L3w[i * 12 + f];
            o = tanhf(s);
        }
        hf[(size_t)v * HFST + f] = __float2half(o);
    }
}

// ---- Edge head: e_row = [hf[src], hf[dst]]; out = e_row @ Cw + Cb ----------
__global__ void k_edge(const int* __restrict__ src, const int* __restrict__ dst,
                       const __half* __restrict__ hf,
                       const float* __restrict__ Cw, const float* __restrict__ Cb,
                       float* __restrict__ out, float* __restrict__ eout, int ne) {
    int e = blockIdx.x * blockDim.x + threadIdx.x;
    if (e >= ne) return;
    int s = src[e], d = dst[e];
    float v[24];
    const __half2* hs = reinterpret_cast<const __half2*>(hf + (size_t)s * HFST);
    const __half2* hd = reinterpret_cast<const __half2*>(hf + (size_t)d * HFST);
    #pragma unroll
    for (int k = 0; k < 6; ++k) {
        float2 t = __half22float2(hs[k]);
        v[2 * k] = t.x; v[2 * k + 1] = t.y;
    }
    #pragma unroll
    for (int k = 0; k < 6; ++k) {
        float2 t = __half22float2(hd[k]);
        v[12 + 2 * k] = t.x; v[12 + 2 * k + 1] = t.y;
    }
    float o0 = Cb[0], o1 = Cb[1], o2 = Cb[2];
    #pragma unroll
    for (int k = 0; k < 24; ++k) {
        o0 += v[k] * Cw[k * 3 + 0];
        o1 += v[k] * Cw[k * 3 + 1];
        o2 += v[k] * Cw[k * 3 + 2];
    }
    float* op = out + (size_t)e * 3;
    op[0] = o0; op[1] = o1; op[2] = o2;
    float4* epv = reinterpret_cast<float4*>(eout + (size_t)e * 24);
    #pragma unroll
    for (int k = 0; k < 6; ++k) epv[k] = reinterpret_cast<const float4*>(v)[k];
}

static inline char* align64(char* p) {
    return (char*)(((uintptr_t)p + 63) & ~(uintptr_t)63);
}

extern "C" void kernel_launch(void* const* d_in, const int* in_sizes, int n_in,
                              void* d_out, int out_size, void* d_ws, size_t ws_size,
                              hipStream_t stream) {
    const float* x  = (const float*)d_in[0];
    const int*   ei = (const int*)d_in[1];
    const int n  = in_sizes[2];
    const int ne = in_sizes[1] / 2;
    const int F  = in_sizes[0] / n;    // 10
    const int* src  = ei;
    const int* dstp = ei + ne;

    const float *W1 = (const float*)d_in[3],  *b1 = (const float*)d_in[4];
    const float *W2 = (const float*)d_in[5],  *b2 = (const float*)d_in[6];
    const float *W3 = (const float*)d_in[7],  *b3 = (const float*)d_in[8];
    const float *L1w = (const float*)d_in[9],  *L1b = (const float*)d_in[10];
    const float *L2w = (const float*)d_in[11], *L2b = (const float*)d_in[12];
    const float *L3w = (const float*)d_in[13], *L3b = (const float*)d_in[14];
    const float *Cw  = (const float*)d_in[15], *Cb  = (const float*)d_in[16];

    // Workspace layout
    char* p = (char*)d_ws;
    int* csr = (int*)p;                    p += (size_t)ne * 4;
    int* epk = (int*)p;                    p += (size_t)ne * 4;
    int* bc  = (int*)p;                    p += (size_t)NB * NBLK * 4;
    int* row = (int*)p;                    p += ((size_t)n + 4) * 4;
    int* bucket_base = (int*)p;            p += ((size_t)NB + 4) * 4;
    int* S   = (int*)p;                    p += ((size_t)NB + 4) * 4;
    float* dinv = (float*)p;               p += (size_t)n * 4;
    p = align64(p);
    __half* g1 = (__half*)p;               p += (size_t)n * ST * 2;
    p = align64(p);
    __half* g2 = (__half*)p;               p += (size_t)n * ST * 2;
    p = align64(p);
    __half* hf = (__half*)p;               p += (size_t)n * HFST * 2;

    const int B = 256;
    const int gb_n32 = (n * 32 + B - 1) / B;
    const int gb_e   = (ne + B - 1) / B;

    // CSR build: LDS counting sort with hierarchical (parallel) scan
    k_p1_hist<<<NBLK, 1024, 0, stream>>>(dstp, ne, bc);
    k_p2a_sum<<<NB, 256, 0, stream>>>(bc, S);
    k_p2b_scan<<<1, 1024, 0, stream>>>(S, bucket_base, row, n, ne);
    k_p2c_scan<<<NB, NBLK, 0, stream>>>(bc, bucket_base);
    k_p3_partition<<<NBLK, 1024, 0, stream>>>(src, dstp, ne, bc, epk);
    k_p4_build<<<NB, B, 0, stream>>>(epk, bucket_base, csr, row, dinv, n);

    // conv1 linear
    k_nl1<<<gb_n32, B, 0, stream>>>(x, F, W1, dinv, g1, n);
    // conv1 gather+finish fused with conv2 linear -> g2
    k_gfnl<18, 24><<<gb_n32, B, 0, stream>>>(row, csr, g1, dinv, b1, W2, g2, n);
    // conv2 gather+finish fused with conv3 linear -> g1
    k_gfnl<24, 20><<<gb_n32, B, 0, stream>>>(row, csr, g2, dinv, b2, W3, g1, n);
    // conv3 gather+finish fused with MLP -> hf (fp16)
    k_gfmlp<<<gb_n32, B, 0, stream>>>(row, csr, g1, dinv, b3,
                                      L1w, L1b, L2w, L2b, L3w, L3b, hf, n);

    // edge head
    float* out_p = (float*)d_out;
    float* e_p   = out_p + (size_t)ne * 3;
    k_edge<<<gb_e, B, 0, stream>>>(src, dstp, hf, Cw, Cb, out_p, e_p, ne);
}